// Round 8
// baseline (9927.388 us; speedup 1.0000x reference)
//
#include <hip/hip_runtime.h>
#include <math.h>

// RNN with short-term plasticity: persistent cooperative kernel, 1 grid
// barrier per time step.
//
// Round 8: cut the coherent A broadcast 4x by moving weights to LDS.
// Total A volume/step = NWG x 128 KB (every WG reads all of A once for
// its owned neurons). Registers capped neurons/WG at 4 (128-VGPR wall,
// rounds 5/6); with masked W staged in LDS (wlds[j][16], 64 KB) a WG
// owns 16 neurons while acc[16][2] needs only 32 VGPRs. NWG=64 -> A
// traffic 32 MB -> 8 MB/step. z now uses in-WG partials (ZP exchange,
// 128 KB/step) instead of the 1.1 MB HT broadcast. Barrier keeps the
// round-4 pattern (per-WG 128B-strided slots; round 7 proved packed
// slots serialize on shared lines).
//
#define NH 1024
#define NB 32
#define NI 8
#define NO 8
#define TSTEPS 1000

#define NWG 64
#define BLK 512

// d_out float offsets (z, h, r, u concatenated flat)
#define OFF_Z 0
#define OFF_H (NB * TSTEPS * NO)            // 256000
#define OFF_R (OFF_H + NB * TSTEPS * NH)    // 33024000
#define OFF_U (OFF_R + NB * TSTEPS * NH)    // 65792000

// d_ws float offsets: slots (64 x 128B), AT[2][NH][NB], ZP[2][NB][NO][64]
#define WS_AT 2048
#define WS_ZP (WS_AT + 2 * NH * NB)

typedef unsigned long long u64;

__device__ __forceinline__ float2 aload2(const float* p) {
    u64 v = __hip_atomic_load((const u64*)p, __ATOMIC_RELAXED,
                              __HIP_MEMORY_SCOPE_AGENT);
    return __builtin_bit_cast(float2, v);
}
__device__ __forceinline__ float aload1(const float* p) {
    return __hip_atomic_load(p, __ATOMIC_RELAXED, __HIP_MEMORY_SCOPE_AGENT);
}
__device__ __forceinline__ void astore(float* p, float v) {
    __hip_atomic_store(p, v, __ATOMIC_RELAXED, __HIP_MEMORY_SCOPE_AGENT);
}

// Barrier: WG g stamps its own 128B-strided slot; wave 0's lane l polls
// slot l. Release ordering: leading __syncthreads drains vmcnt in every
// wave (agent stores ack'd at the coherence point) before the stamp.
__device__ __forceinline__ void gridbar(unsigned* slot, int g, unsigned stamp) {
    __syncthreads();
    if (threadIdx.x == 0)
        __hip_atomic_store(&slot[g * 32], stamp,
                           __ATOMIC_RELAXED, __HIP_MEMORY_SCOPE_AGENT);
    if (threadIdx.x < NWG) {
        while (__hip_atomic_load(&slot[threadIdx.x * 32],
                                 __ATOMIC_RELAXED, __HIP_MEMORY_SCOPE_AGENT) < stamp)
            __builtin_amdgcn_s_sleep(1);
    }
    __syncthreads();
}

__global__ __launch_bounds__(BLK, 2) void rnn_stp_kernel(
    const float* __restrict__ x,     // [32][1000][8]
    const float* __restrict__ h0,    // [32][1024]
    const float* __restrict__ r0,    // [32][1024]
    const float* __restrict__ u0,    // [32][1024]
    const float* __restrict__ prel,  // [1024]
    const float* __restrict__ scal,  // [1024]
    const float* __restrict__ Wih,   // [1024][8]
    const float* __restrict__ Whh,   // [1024][1024]
    const float* __restrict__ Wmask, // [1024][1024]
    const float* __restrict__ Whz,   // [8][1024]
    float* __restrict__ out,
    float* __restrict__ ws)
{
    const int tid = threadIdx.x;
    const int g   = blockIdx.x;

    unsigned* slot = (unsigned*)ws;
    float* AT = ws + WS_AT;   // [2][NH][NB]
    float* ZP = ws + WS_ZP;   // [2][NB][NO][64]

    const int ib = g * 16;    // 16 owned neurons; one full 64B out-line per WG

    __shared__ float wlds[NH * 16];      // [j][il]  64 KB
    __shared__ float red[8 * 16 * 36];   // [wid][bg][36]  18 KB

    const int lane = tid & 63, wid = tid >> 6;

    // ---- GEMM roles: ks = tid>>4 (j in {c*32+ks}), bg = tid&15 (2 b) ----
    const int ks = tid >> 4;
    const int bg = tid & 15;

    // ---- owner role: every thread owns (b = tid>>4, neuron = ib + tid&15) ----
    const int ob   = tid >> 4;
    const int il_o = tid & 15;
    const int oi   = ib + il_o;

    // ---- stage masked weights into LDS: wlds[j][il] ----
    {
        const int sil = tid & 15;
        const int sjb = (tid >> 4) * 32;
        const float* wp = Whh   + (ib + sil) * NH + sjb;
        const float* mp = Wmask + (ib + sil) * NH + sjb;
        #pragma unroll 8
        for (int jj = 0; jj < 32; ++jj)
            wlds[(sjb + jj) * 16 + sil] = wp[jj] * mp[jj];
    }

    // ---- owner init ----
    float h  = h0[ob * NH + oi];
    float r  = r0[ob * NH + oi];
    float u  = u0[ob * NH + oi];
    const float p  = prel[oi];
    const float sc = scal[oi];
    float wih[8];
    #pragma unroll
    for (int k = 0; k < 8; ++k) wih[k] = Wih[oi * NI + k];
    float wz[8];
    #pragma unroll
    for (int o = 0; o < 8; ++o) wz[o] = Whz[o * NH + oi];
    float htr = tanhf(h);
    astore(&AT[oi * NB + ob], r * sc * htr);

    unsigned stamp = 1;
    gridbar(slot, g, stamp); ++stamp;

    const int gb = bg * 2;    // first batch of this thread's GEMM pair

    for (int t = 0; t < TSTEPS; ++t) {
        const int par = t & 1;

        // ---- GEMM: software-pipelined 8-j chunks of coherent A loads ----
        const float* Abase = AT + par * NH * NB + ks * NB + gb;
        float acc[16][2];
        #pragma unroll
        for (int il = 0; il < 16; ++il) { acc[il][0] = 0.f; acc[il][1] = 0.f; }

        float2 aE[8], aO[8];

#define LOADC(buf, cc)                                                    \
        _Pragma("unroll")                                                 \
        for (int q = 0; q < 8; ++q)                                       \
            buf[q] = aload2(Abase + ((cc) * 8 + q) * (32 * NB));

#define FMAC(buf, cc)                                                     \
        _Pragma("unroll")                                                 \
        for (int q = 0; q < 8; ++q) {                                     \
            const int j = ((cc) * 8 + q) * 32 + ks;                       \
            const float4* wp4 = (const float4*)(wlds + j * 16);           \
            float4 w0 = wp4[0], w1 = wp4[1], w2 = wp4[2], w3 = wp4[3];    \
            const float wv[16] = { w0.x,w0.y,w0.z,w0.w, w1.x,w1.y,w1.z,w1.w, \
                                   w2.x,w2.y,w2.z,w2.w, w3.x,w3.y,w3.z,w3.w };\
            float2 a = buf[q];                                            \
            _Pragma("unroll")                                             \
            for (int il = 0; il < 16; ++il) {                             \
                acc[il][0] = fmaf(a.x, wv[il], acc[il][0]);               \
                acc[il][1] = fmaf(a.y, wv[il], acc[il][1]);               \
            }                                                             \
        }

        LOADC(aE, 0);
        LOADC(aO, 1); FMAC(aE, 0);
        LOADC(aE, 2); FMAC(aO, 1);
        LOADC(aO, 3); FMAC(aE, 2);
        FMAC(aO, 3);
#undef LOADC
#undef FMAC

        // ---- butterfly over the wave's 4 ks groups (lane bits 4,5) ----
        #pragma unroll
        for (int m = 16; m <= 32; m <<= 1) {
            #pragma unroll
            for (int il = 0; il < 16; ++il) {
                acc[il][0] += __shfl_xor(acc[il][0], m, 64);
                acc[il][1] += __shfl_xor(acc[il][1], m, 64);
            }
        }
        if (lane < 16) {   // lane == bg: wave-level partial for 8-wave combine
            float* rp = red + wid * 576 + bg * 36;
            #pragma unroll
            for (int i4 = 0; i4 < 8; ++i4)
                ((float4*)rp)[i4] = make_float4(acc[2*i4][0], acc[2*i4][1],
                                                acc[2*i4+1][0], acc[2*i4+1][1]);
        }
        __syncthreads();

        // ---- finalize z[t-1]: waves 0..3, pair = 4g+wid ----
        if (t >= 1 && wid < 4) {
            const int pair = g * 4 + wid;
            const int bzf = pair >> 3, ozf = pair & 7;
            float v = aload1(ZP + ((t - 1) & 1) * (NB * NO * 64)
                             + bzf * (NO * 64) + ozf * 64 + lane);
            #pragma unroll
            for (int m = 1; m < 64; m <<= 1) v += __shfl_xor(v, m, 64);
            if (lane == 0)
                out[OFF_Z + (bzf * TSTEPS + (t - 1)) * NO + ozf] = v;
        }

        // ---- owner: gather partials, update state, write outputs ----
        {
            float rec = 0.f;
            #pragma unroll
            for (int wv = 0; wv < 8; ++wv)
                rec += red[wv * 576 + (ob >> 1) * 36 + il_o * 2 + (ob & 1)];

            const float4* xp = (const float4*)(x + (ob * TSTEPS + t) * NI);
            float4 xa = xp[0], xb = xp[1];
            float xv = fmaf(xa.x, wih[0], fmaf(xa.y, wih[1],
                       fmaf(xa.z, wih[2], xa.w * wih[3])));
            xv = fmaf(xb.x, wih[4], fmaf(xb.y, wih[5],
                 fmaf(xb.z, wih[6], fmaf(xb.w, wih[7], xv))));

            float drive = 0.5f * (1.0f + htr);
            float rn = r + ((p - r) / 0.2f - 10.0f * r * drive) * 0.001f;
            float un = u + ((p - u) / 1.5f + 10.0f * (1.0f - u) * drive) * 0.001f;
            float hn = h + ((-h + xv + rec) / 0.01f) * 0.001f;
            float htn = tanhf(hn);

            out[OFF_H + (ob * TSTEPS + t) * NH + oi] = hn;
            out[OFF_R + (ob * TSTEPS + t) * NH + oi] = rn;
            out[OFF_U + (ob * TSTEPS + t) * NH + oi] = un;

            astore(&AT[(par ^ 1) * NH * NB + oi * NB + ob], rn * sc * htn);

            // z partial for step t: reduce htn*wz over the 16 il lanes
            float zp_[8];
            #pragma unroll
            for (int o = 0; o < 8; ++o) zp_[o] = htn * wz[o];
            #pragma unroll
            for (int m = 1; m <= 8; m <<= 1) {
                #pragma unroll
                for (int o = 0; o < 8; ++o)
                    zp_[o] += __shfl_xor(zp_[o], m, 64);
            }
            if (il_o == 0) {
                float* zpp = ZP + par * (NB * NO * 64) + ob * (NO * 64) + g;
                #pragma unroll
                for (int o = 0; o < 8; ++o) astore(zpp + o * 64, zp_[o]);
            }

            h = hn; r = rn; u = un; htr = htn;
        }

        gridbar(slot, g, stamp); ++stamp;
    }

    // ---- epilogue: finalize z[999] (par 1, written at t=999) ----
    if (wid < 4) {
        const int pair = g * 4 + wid;
        const int bzf = pair >> 3, ozf = pair & 7;
        float v = aload1(ZP + 1 * (NB * NO * 64)
                         + bzf * (NO * 64) + ozf * 64 + lane);
        #pragma unroll
        for (int m = 1; m < 64; m <<= 1) v += __shfl_xor(v, m, 64);
        if (lane == 0)
            out[OFF_Z + (bzf * TSTEPS + 999) * NO + ozf] = v;
    }
}

extern "C" void kernel_launch(void* const* d_in, const int* in_sizes, int n_in,
                              void* d_out, int out_size, void* d_ws, size_t ws_size,
                              hipStream_t stream) {
    const float* x     = (const float*)d_in[0];
    const float* h0    = (const float*)d_in[1];
    const float* r0    = (const float*)d_in[2];
    const float* u0    = (const float*)d_in[3];
    const float* prel  = (const float*)d_in[4];
    const float* scal  = (const float*)d_in[5];
    const float* Wih   = (const float*)d_in[6];
    const float* Whh   = (const float*)d_in[7];
    const float* Wmask = (const float*)d_in[8];
    const float* Whz   = (const float*)d_in[9];
    float* out = (float*)d_out;
    float* ws  = (float*)d_ws;

    // Zero the 64 barrier slots (128B apart) each launch.
    hipMemsetAsync(d_ws, 0, NWG * 128, stream);

    void* args[] = { &x, &h0, &r0, &u0, &prel, &scal,
                     &Wih, &Whh, &Wmask, &Whz, &out, &ws };
    hipLaunchCooperativeKernel((void*)rnn_stp_kernel, dim3(NWG), dim3(BLK),
                               args, 0, stream);
}

// Round 9
// 6810.305 us; speedup vs baseline: 1.4577x; 1.4577x over previous
//
#include <hip/hip_runtime.h>
#include <math.h>

// RNN with short-term plasticity: persistent cooperative kernel.
//
// Round 9: exploit batch-independence. The recurrence never couples
// batches, so the grid splits into 8 INDEPENDENT groups of 32 WGs;
// group G owns batches [4G,4G+4). Each WG (member m) owns neurons
// [32m,32m+32) for its group's 4 batches: w[2][32]=64 VGPRs (the
// round-4-proven budget; rounds 5/6 showed >64 spills at the hard
// 128-VGPR wall). Per-step coherent A volume: 256 WG x 16 KB = 4 MB
// (8x less than round 4's 32 MB); A staged through LDS with a
// 33-float4-stride pad so ks-group broadcast reads are conflict-free.
// Barrier is per-group: 32 slots, 128B apart (round 7: packed slots
// serialize on shared lines). z done in-group: per-WG shfl partials ->
// coherent ZP exchange -> finalize lags one step.
//
#define NH 1024
#define NB 32
#define NI 8
#define NO 8
#define TSTEPS 1000

#define NWG 256
#define BLK 512
#define NG 8          // independent groups
#define NM 32         // members (WGs) per group
#define GBATCH 4      // batches per group

// d_out float offsets (z, h, r, u concatenated flat)
#define OFF_Z 0
#define OFF_H (NB * TSTEPS * NO)            // 256000
#define OFF_R (OFF_H + NB * TSTEPS * NH)    // 33024000
#define OFF_U (OFF_R + NB * TSTEPS * NH)    // 65792000

// d_ws float offsets: slots 256x128B = 32 KB, then A, then ZP
#define WS_A  8192                               // A[2][NG][NH][GBATCH]
#define WS_ZP (WS_A + 2 * NG * NH * GBATCH)      // ZP[2][NG][GBATCH][NO][NM]

typedef unsigned long long u64;

__device__ __forceinline__ float2 aload2(const float* p) {
    u64 v = __hip_atomic_load((const u64*)p, __ATOMIC_RELAXED,
                              __HIP_MEMORY_SCOPE_AGENT);
    return __builtin_bit_cast(float2, v);
}
__device__ __forceinline__ float aload1(const float* p) {
    return __hip_atomic_load(p, __ATOMIC_RELAXED, __HIP_MEMORY_SCOPE_AGENT);
}
__device__ __forceinline__ void astore(float* p, float v) {
    __hip_atomic_store(p, v, __ATOMIC_RELAXED, __HIP_MEMORY_SCOPE_AGENT);
}

// Per-group barrier: member m stamps slot [G][m] (128B-strided); lanes<32
// of wave 0 poll the group's 32 slots. Release ordering: the leading
// __syncthreads drains vmcnt in every wave (all agent-scope stores ack'd
// at the coherence point) before thread 0 stamps.
__device__ __forceinline__ void groupbar(unsigned* slot, int G, int m,
                                         unsigned stamp) {
    __syncthreads();
    if (threadIdx.x == 0)
        __hip_atomic_store(&slot[(G * NM + m) * 32], stamp,
                           __ATOMIC_RELAXED, __HIP_MEMORY_SCOPE_AGENT);
    if (threadIdx.x < NM) {
        while (__hip_atomic_load(&slot[(G * NM + threadIdx.x) * 32],
                                 __ATOMIC_RELAXED, __HIP_MEMORY_SCOPE_AGENT)
               < stamp)
            __builtin_amdgcn_s_sleep(1);
    }
    __syncthreads();
}

__global__ __launch_bounds__(BLK, 2) void rnn_stp_kernel(
    const float* __restrict__ x,     // [32][1000][8]
    const float* __restrict__ h0,    // [32][1024]
    const float* __restrict__ r0,    // [32][1024]
    const float* __restrict__ u0,    // [32][1024]
    const float* __restrict__ prel,  // [1024]
    const float* __restrict__ scal,  // [1024]
    const float* __restrict__ Wih,   // [1024][8]
    const float* __restrict__ Whh,   // [1024][1024]
    const float* __restrict__ Wmask, // [1024][1024]
    const float* __restrict__ Whz,   // [8][1024]
    float* __restrict__ out,
    float* __restrict__ ws)
{
    const int tid = threadIdx.x;
    const int g   = blockIdx.x;

    // g&7 -> XCD heuristic: members of a group land on distinct XCD slots;
    // G = g&7 keeps each group's 32 members on ONE XCD (locality only —
    // correctness never depends on placement).
    const int G = g & 7;
    const int m = g >> 3;

    unsigned* slot = (unsigned*)ws;
    float* Abuf = ws + WS_A;    // [2][NG][NH][GBATCH]
    float* ZP   = ws + WS_ZP;   // [2][NG][GBATCH][NO][NM]

    // LDS: A-tile padded to 33 float4 per 32 rows (row j -> float4 33*ks+jj)
    __shared__ float4 atile[NM * 33];          // 16.9 KB
    __shared__ float  red[8 * 16 * 9];         // 4.6 KB
    __shared__ float  hbuf[GBATCH][NM];        // 512 B

    const int lane = tid & 63, wid = tid >> 6;

    // ---- GEMM roles: ks = tid>>4 (j in [32ks,32ks+32)), il = tid&15 ----
    const int ks = tid >> 4;
    const int il = tid & 15;

    // Masked weights: w[nn][jj] = Weff[32m + il + 16nn][32ks + jj]
    float w[2][32];
    #pragma unroll
    for (int nn = 0; nn < 2; ++nn) {
        const int row = 32 * m + il + 16 * nn;
        const float* wp = Whh   + row * NH + 32 * ks;
        const float* mp = Wmask + row * NH + 32 * ks;
        #pragma unroll
        for (int jj = 0; jj < 32; ++jj) w[nn][jj] = wp[jj] * mp[jj];
    }

    // ---- owner role: tid<128: local batch ob = tid>>5, neuron on = tid&31 ----
    const bool own = tid < 128;
    const int ob = tid >> 5;
    const int on = tid & 31;
    const int bglob = G * GBATCH + ob;
    const int oi = 32 * m + on;
    float h = 0.f, r = 0.f, u = 0.f, htr = 0.f, p = 0.f, sc = 0.f;
    float wih[8];
    if (own) {
        h  = h0[bglob * NH + oi];
        r  = r0[bglob * NH + oi];
        u  = u0[bglob * NH + oi];
        p  = prel[oi];
        sc = scal[oi];
        #pragma unroll
        for (int k = 0; k < 8; ++k) wih[k] = Wih[oi * NI + k];
        htr = tanhf(h);
        astore(&Abuf[G * (NH * GBATCH) + oi * GBATCH + ob], r * sc * htr);
    }

    // ---- z-partial consts (waves 0..3): o = lane>>3, nsub = lane&7 ----
    float wzv[4];
    #pragma unroll
    for (int k = 0; k < 4; ++k)
        wzv[k] = Whz[(lane >> 3) * NH + 32 * m + (lane & 7) + 8 * k];
    // ---- z-finalize consts (wave 4, lanes<32): member m -> (bf, of) ----
    const int bf = m >> 3, of = m & 7;

    unsigned stamp = 1;
    groupbar(slot, G, m, stamp); ++stamp;

    for (int t = 0; t < TSTEPS; ++t) {
        const int par = t & 1;

        // ---- stage A[par][G] (16 KB) into LDS; 8 floats (2 rows) per thread ----
        const float* Ag = Abuf + par * (NG * NH * GBATCH) + G * (NH * GBATCH);
        {
            float2 s0 = aload2(Ag + tid * 8 + 0);
            float2 s1 = aload2(Ag + tid * 8 + 2);
            float2 s2 = aload2(Ag + tid * 8 + 4);
            float2 s3 = aload2(Ag + tid * 8 + 6);
            const int r0i = tid * 2;           // rows r0i, r0i+1
            atile[r0i + (r0i >> 5)]     = make_float4(s0.x, s0.y, s1.x, s1.y);
            atile[r0i + 1 + (r0i >> 5)] = make_float4(s2.x, s2.y, s3.x, s3.y);
        }

        // ---- x prefetch for owners (cached, latency-tolerant) ----
        float4 xa = make_float4(0.f, 0.f, 0.f, 0.f), xb = xa;
        if (own) {
            const float4* xp = (const float4*)(x + (bglob * TSTEPS + t) * NI);
            xa = xp[0];
            xb = xp[1];
        }
        __syncthreads();

        // ---- GEMM: 32 j x 2 nn x 4 b from LDS (broadcast, conflict-free) ----
        float acc[2][4] = {{0.f,0.f,0.f,0.f},{0.f,0.f,0.f,0.f}};
        {
            const float4* at4 = atile + 33 * ks;
            #pragma unroll 8
            for (int jj = 0; jj < 32; ++jj) {
                float4 a = at4[jj];
                const float w0 = w[0][jj], w1 = w[1][jj];
                acc[0][0] = fmaf(a.x, w0, acc[0][0]);
                acc[0][1] = fmaf(a.y, w0, acc[0][1]);
                acc[0][2] = fmaf(a.z, w0, acc[0][2]);
                acc[0][3] = fmaf(a.w, w0, acc[0][3]);
                acc[1][0] = fmaf(a.x, w1, acc[1][0]);
                acc[1][1] = fmaf(a.y, w1, acc[1][1]);
                acc[1][2] = fmaf(a.z, w1, acc[1][2]);
                acc[1][3] = fmaf(a.w, w1, acc[1][3]);
            }
        }

        // ---- butterfly over ks low bits (lane bits 4,5) ----
        #pragma unroll
        for (int mm = 16; mm <= 32; mm <<= 1) {
            #pragma unroll
            for (int nn = 0; nn < 2; ++nn) {
                #pragma unroll
                for (int q = 0; q < 4; ++q)
                    acc[nn][q] += __shfl_xor(acc[nn][q], mm, 64);
            }
        }
        if (lane < 16) {
            float* rp = red + (wid * 16 + lane) * 9;
            rp[0] = acc[0][0]; rp[1] = acc[0][1];
            rp[2] = acc[0][2]; rp[3] = acc[0][3];
            rp[4] = acc[1][0]; rp[5] = acc[1][1];
            rp[6] = acc[1][2]; rp[7] = acc[1][3];
        }
        __syncthreads();

        // ---- owner: combine 8 wave partials, update state, write out ----
        if (own) {
            float rec = 0.f;
            #pragma unroll
            for (int wv = 0; wv < 8; ++wv)
                rec += red[(wv * 16 + (on & 15)) * 9 + (on >> 4) * 4 + ob];

            float xv = fmaf(xa.x, wih[0], fmaf(xa.y, wih[1],
                       fmaf(xa.z, wih[2], xa.w * wih[3])));
            xv = fmaf(xb.x, wih[4], fmaf(xb.y, wih[5],
                 fmaf(xb.z, wih[6], fmaf(xb.w, wih[7], xv))));

            float drive = 0.5f * (1.0f + htr);
            float rn = r + ((p - r) / 0.2f - 10.0f * r * drive) * 0.001f;
            float un = u + ((p - u) / 1.5f + 10.0f * (1.0f - u) * drive) * 0.001f;
            float hn = h + ((-h + xv + rec) / 0.01f) * 0.001f;
            float htn = tanhf(hn);

            out[OFF_H + (bglob * TSTEPS + t) * NH + oi] = hn;
            out[OFF_R + (bglob * TSTEPS + t) * NH + oi] = rn;
            out[OFF_U + (bglob * TSTEPS + t) * NH + oi] = un;

            astore(&Abuf[(par ^ 1) * (NG * NH * GBATCH) + G * (NH * GBATCH)
                         + oi * GBATCH + ob], rn * sc * htn);
            hbuf[ob][on] = htn;

            h = hn; r = rn; u = un; htr = htn;
        }
        __syncthreads();   // hbuf visible to z-partial waves

        // ---- z partials for step t: waves 0..3 (b = wid) ----
        if (wid < 4) {
            const int o = lane >> 3, ns = lane & 7;
            float zp = 0.f;
            #pragma unroll
            for (int k = 0; k < 4; ++k)
                zp = fmaf(hbuf[wid][ns + 8 * k], wzv[k], zp);
            zp += __shfl_xor(zp, 1, 64);
            zp += __shfl_xor(zp, 2, 64);
            zp += __shfl_xor(zp, 4, 64);
            if (ns == 0)
                astore(&ZP[par * (NG * GBATCH * NO * NM)
                           + G * (GBATCH * NO * NM)
                           + wid * (NO * NM) + o * NM + m], zp);
        }
        // ---- z finalize for step t-1: wave 4, lanes<32 ----
        if (t >= 1 && wid == 4 && lane < NM) {
            float v = aload1(ZP + (par ^ 1) * (NG * GBATCH * NO * NM)
                             + G * (GBATCH * NO * NM)
                             + bf * (NO * NM) + of * NM + lane);
            v += __shfl_xor(v, 1, 64);
            v += __shfl_xor(v, 2, 64);
            v += __shfl_xor(v, 4, 64);
            v += __shfl_xor(v, 8, 64);
            v += __shfl_xor(v, 16, 64);
            if (lane == 0)
                out[OFF_Z + ((G * GBATCH + bf) * TSTEPS + (t - 1)) * NO + of] = v;
        }

        groupbar(slot, G, m, stamp); ++stamp;
    }

    // ---- epilogue: finalize z[999] (partials in ZP[1]) ----
    if (wid == 4 && lane < NM) {
        float v = aload1(ZP + 1 * (NG * GBATCH * NO * NM)
                         + G * (GBATCH * NO * NM)
                         + bf * (NO * NM) + of * NM + lane);
        v += __shfl_xor(v, 1, 64);
        v += __shfl_xor(v, 2, 64);
        v += __shfl_xor(v, 4, 64);
        v += __shfl_xor(v, 8, 64);
        v += __shfl_xor(v, 16, 64);
        if (lane == 0)
            out[OFF_Z + ((G * GBATCH + bf) * TSTEPS + 999) * NO + of] = v;
    }
}

extern "C" void kernel_launch(void* const* d_in, const int* in_sizes, int n_in,
                              void* d_out, int out_size, void* d_ws, size_t ws_size,
                              hipStream_t stream) {
    const float* x     = (const float*)d_in[0];
    const float* h0    = (const float*)d_in[1];
    const float* r0    = (const float*)d_in[2];
    const float* u0    = (const float*)d_in[3];
    const float* prel  = (const float*)d_in[4];
    const float* scal  = (const float*)d_in[5];
    const float* Wih   = (const float*)d_in[6];
    const float* Whh   = (const float*)d_in[7];
    const float* Wmask = (const float*)d_in[8];
    const float* Whz   = (const float*)d_in[9];
    float* out = (float*)d_out;
    float* ws  = (float*)d_ws;

    // Zero the 256 barrier slots (128B apart) each launch.
    hipMemsetAsync(d_ws, 0, NWG * 128, stream);

    void* args[] = { &x, &h0, &r0, &u0, &prel, &scal,
                     &Wih, &Whh, &Wmask, &Whz, &out, &ws };
    hipLaunchCooperativeKernel((void*)rnn_stp_kernel, dim3(NWG), dim3(BLK),
                               args, 0, stream);
}